// Round 1
// baseline (133.280 us; speedup 1.0000x reference)
//
#include <hip/hip_runtime.h>
#include <hip/hip_bf16.h>
#include <stdint.h>

typedef __attribute__((ext_vector_type(8))) short short8;
typedef __attribute__((ext_vector_type(4))) float f32x4;

// fp32 -> bf16 bits, round-to-nearest-even
static __device__ __forceinline__ short f2bf(float f) {
    union { float f; uint32_t u; } v; v.f = f;
    uint32_t u = v.u;
    uint32_t r = (u + 0x7FFFu + ((u >> 16) & 1u)) >> 16;
    return (short)r;
}

// Kernel 1: per-code squared norms ws[64 + g*512 + k], and zero loss accumulator ws[0]
__global__ void vq_wsq_kernel(const float* __restrict__ w0, const float* __restrict__ w1,
                              const float* __restrict__ w2, const float* __restrict__ w3,
                              float* __restrict__ ws) {
    int tid = blockIdx.x * blockDim.x + threadIdx.x; // 0..2047
    if (tid == 0) ws[0] = 0.f;
    const float* wg = (tid < 512) ? w0 : (tid < 1024) ? w1 : (tid < 1536) ? w2 : w3;
    int row = tid & 511;
    const float4* p = (const float4*)(wg + row * 128);
    float s = 0.f;
    #pragma unroll
    for (int i = 0; i < 32; i++) {
        float4 v = p[i];
        s += v.x*v.x + v.y*v.y + v.z*v.z + v.w*v.w;
    }
    ws[64 + tid] = s;
}

// Kernel 2: main fused VQ
// grid: 512 blocks (128 per group), 256 threads (4 waves), 256 tokens/block
__global__ void vq_main_kernel(const float* __restrict__ lat,
                               const float* __restrict__ w0, const float* __restrict__ w1,
                               const float* __restrict__ w2, const float* __restrict__ w3,
                               float* __restrict__ out, float* __restrict__ ws) {
    __shared__ __align__(16) short lw[64 * 128];  // swizzled bf16 codebook chunk (16 KB)
    __shared__ float lwsq[512];
    __shared__ int   sidx[256];

    const int bid   = blockIdx.x;            // 0..511
    const int g     = bid >> 7;              // 0..3
    const int tbase = (bid & 127) * 256;     // token base within group token space
    const float* wg = (g == 0) ? w0 : (g == 1) ? w1 : (g == 2) ? w2 : w3;

    const int t    = threadIdx.x;
    const int wave = t >> 6;
    const int l    = t & 63;
    const int lr   = l & 15;                 // tile row (A) / col (B,C)
    const int lh   = l >> 4;                 // 0..3: k-partition / C row-block

    // stage wsq for this group into LDS
    lwsq[t]       = ws[64 + g * 512 + t];
    lwsq[t + 256] = ws[64 + g * 512 + t + 256];

    // Load A fragments (64 tokens per wave) global->reg, bf16; fp32 x_sq on the fly.
    short8 afrag[4][4];
    float  xsq[4];
    const int wtok = tbase + wave * 64;
    #pragma unroll
    for (int mt = 0; mt < 4; mt++) {
        int token = wtok + mt * 16 + lr;
        const float* xp = lat + (size_t)token * 512 + g * 128 + lh * 8;
        float part = 0.f;
        #pragma unroll
        for (int ks = 0; ks < 4; ks++) {
            float4 v0 = *(const float4*)(xp + ks * 32);
            float4 v1 = *(const float4*)(xp + ks * 32 + 4);
            part += v0.x*v0.x + v0.y*v0.y + v0.z*v0.z + v0.w*v0.w
                  + v1.x*v1.x + v1.y*v1.y + v1.z*v1.z + v1.w*v1.w;
            short8 a;
            a[0] = f2bf(v0.x); a[1] = f2bf(v0.y); a[2] = f2bf(v0.z); a[3] = f2bf(v0.w);
            a[4] = f2bf(v1.x); a[5] = f2bf(v1.y); a[6] = f2bf(v1.z); a[7] = f2bf(v1.w);
            afrag[mt][ks] = a;
        }
        part += __shfl_xor(part, 16);
        part += __shfl_xor(part, 32);
        xsq[mt] = part;   // full 128-elem sum; indexed by row = lr
    }

    float runval[16];
    int   runidx[16];
    #pragma unroll
    for (int i = 0; i < 16; i++) { runval[i] = 3.4e38f; runidx[i] = 0; }

    for (int chunk = 0; chunk < 8; chunk++) {
        __syncthreads();
        // stage 64 codes (fp32 -> bf16) into swizzled LDS
        #pragma unroll
        for (int p = 0; p < 4; p++) {
            int row = p * 16 + (t >> 4);
            int col = (t & 15) * 8;
            const float* wp = wg + (size_t)(chunk * 64 + row) * 128 + col;
            float4 v0 = *(const float4*)(wp);
            float4 v1 = *(const float4*)(wp + 4);
            short8 b;
            b[0] = f2bf(v0.x); b[1] = f2bf(v0.y); b[2] = f2bf(v0.z); b[3] = f2bf(v0.w);
            b[4] = f2bf(v1.x); b[5] = f2bf(v1.y); b[6] = f2bf(v1.z); b[7] = f2bf(v1.w);
            int byteoff = (row * 256 + col * 2) ^ ((row & 7) << 4);
            *(short8*)((char*)lw + byteoff) = b;
        }
        __syncthreads();

        #pragma unroll
        for (int nt = 0; nt < 4; nt++) {
            short8 bfrag[4];
            #pragma unroll
            for (int ks = 0; ks < 4; ks++) {
                int row = nt * 16 + lr;
                int byteoff = (row * 256 + ks * 64 + lh * 16) ^ ((row & 7) << 4);
                bfrag[ks] = *(const short8*)((const char*)lw + byteoff);
            }
            int codebase = chunk * 64 + nt * 16;
            float half_wsq = 0.5f * lwsq[codebase + lr];
            #pragma unroll
            for (int mt = 0; mt < 4; mt++) {
                f32x4 acc = {0.f, 0.f, 0.f, 0.f};
                #pragma unroll
                for (int ks = 0; ks < 4; ks++)
                    acc = __builtin_amdgcn_mfma_f32_16x16x32_bf16(afrag[mt][ks], bfrag[ks], acc, 0, 0, 0);
                int code = codebase + lr;
                #pragma unroll
                for (int r = 0; r < 4; r++) {
                    float s = half_wsq - acc[r];   // 0.5*||w||^2 - x.w
                    int i = mt * 4 + r;
                    if (s < runval[i]) { runval[i] = s; runidx[i] = code; }
                }
            }
        }
    }

    // argmin across the 16 lanes of each row-group (cols), lexicographic tie-break
    #pragma unroll
    for (int i = 0; i < 16; i++) {
        float v = runval[i]; int id = runidx[i];
        #pragma unroll
        for (int m = 1; m < 16; m <<= 1) {
            float ov = __shfl_xor(v, m);
            int   oi = __shfl_xor(id, m);
            if (ov < v || (ov == v && oi < id)) { v = ov; id = oi; }
        }
        runval[i] = v; runidx[i] = id;
    }

    // per-token min distance, loss accumulation, stash indices
    float lsum = 0.f;
    #pragma unroll
    for (int mt = 0; mt < 4; mt++) {
        #pragma unroll
        for (int r = 0; r < 4; r++) {
            int row = lh * 4 + r;   // row within m-tile owned by this lane-group
            float xs = __shfl(xsq[mt], (l & 48) | row);
            float dist = xs + 2.f * runval[mt * 4 + r];
            if (lr == 0) {
                lsum += dist;
                sidx[wave * 64 + mt * 16 + row] = runidx[mt * 4 + r];
            }
        }
    }
    lsum += __shfl_xor(lsum, 16);
    lsum += __shfl_xor(lsum, 32);
    if (l == 0) atomicAdd(&ws[0], lsum);

    // write q = w[idx] (exact fp32 codebook rows)
    __syncthreads();
    #pragma unroll
    for (int i = 0; i < 16; i++) {
        int tloc = i * 16 + (t >> 4);
        int idx  = sidx[tloc];
        const float4* src = (const float4*)(wg + (size_t)idx * 128 + (t & 15) * 8);
        float4* dst = (float4*)(out + (size_t)(tbase + tloc) * 512 + g * 128 + (t & 15) * 8);
        dst[0] = src[0];
        dst[1] = src[1];
    }
}

// Kernel 3: finalize loss
__global__ void vq_finalize_kernel(const float* __restrict__ ws, float* __restrict__ out) {
    out[16777216] = 1.25f * ws[0] * (1.0f / 4194304.0f);
}

extern "C" void kernel_launch(void* const* d_in, const int* in_sizes, int n_in,
                              void* d_out, int out_size, void* d_ws, size_t ws_size,
                              hipStream_t stream) {
    const float* lat = (const float*)d_in[0];
    const float* w1  = (const float*)d_in[1];
    const float* w2  = (const float*)d_in[2];
    const float* w3  = (const float*)d_in[3];
    const float* w4  = (const float*)d_in[4];
    float* out = (float*)d_out;
    float* ws  = (float*)d_ws;

    vq_wsq_kernel<<<8, 256, 0, stream>>>(w1, w2, w3, w4, ws);
    vq_main_kernel<<<512, 256, 0, stream>>>(lat, w1, w2, w3, w4, out, ws);
    vq_finalize_kernel<<<1, 1, 0, stream>>>(ws, out);
}

// Round 2
// 96.230 us; speedup vs baseline: 1.3850x; 1.3850x over previous
//
#include <hip/hip_runtime.h>
#include <hip/hip_bf16.h>
#include <stdint.h>

typedef __attribute__((ext_vector_type(8))) short short8;
typedef __attribute__((ext_vector_type(4))) float f32x4;

// fp32 -> bf16 bits, round-to-nearest-even
static __device__ __forceinline__ short f2bf(float f) {
    union { float f; uint32_t u; } v; v.f = f;
    uint32_t u = v.u;
    uint32_t r = (u + 0x7FFFu + ((u >> 16) & 1u)) >> 16;
    return (short)r;
}

static __device__ __forceinline__ void gload_lds16(const void* g, void* l) {
    __builtin_amdgcn_global_load_lds(
        (const __attribute__((address_space(1))) unsigned int*)g,
        (__attribute__((address_space(3))) unsigned int*)l, 16, 0, 0);
}

// ws layout:
//   ws[0]            : loss accumulator (float)
//   ws[64 .. 64+2048): per-code squared norms, group-major (4 x 512)
//   byte offset 65536: bf16 codebooks, pre-swizzled, group-major:
//                      per group 8 chunks x 16384 B; within a chunk, element
//                      (row 0..63, col 0..127) lives at byte
//                      (row*256 + col*2) ^ ((row&7)<<4)

// Kernel 1: norms + bf16 swizzled codebook. 2048 threads, one per code row.
__global__ void vq_prep_kernel(const float* __restrict__ w0, const float* __restrict__ w1,
                               const float* __restrict__ w2, const float* __restrict__ w3,
                               float* __restrict__ ws) {
    int tid = blockIdx.x * blockDim.x + threadIdx.x; // 0..2047
    if (tid == 0) ws[0] = 0.f;
    const float* wg = (tid < 512) ? w0 : (tid < 1024) ? w1 : (tid < 1536) ? w2 : w3;
    int code = tid & 511;
    const float* src = wg + (size_t)code * 128;
    // destination chunk buffer for this code
    char* cb = (char*)ws + 65536 + (size_t)(tid >> 9) * 65536 + (size_t)(code >> 6) * 16384;
    int lrow = code & 63;
    float s = 0.f;
    #pragma unroll
    for (int cg = 0; cg < 16; cg++) {
        float4 v0 = *(const float4*)(src + cg * 8);
        float4 v1 = *(const float4*)(src + cg * 8 + 4);
        s += v0.x*v0.x + v0.y*v0.y + v0.z*v0.z + v0.w*v0.w
           + v1.x*v1.x + v1.y*v1.y + v1.z*v1.z + v1.w*v1.w;
        short8 b;
        b[0] = f2bf(v0.x); b[1] = f2bf(v0.y); b[2] = f2bf(v0.z); b[3] = f2bf(v0.w);
        b[4] = f2bf(v1.x); b[5] = f2bf(v1.y); b[6] = f2bf(v1.z); b[7] = f2bf(v1.w);
        int byteoff = (lrow * 256 + cg * 16) ^ ((lrow & 7) << 4);
        *(short8*)(cb + byteoff) = b;
    }
    ws[64 + tid] = s;
}

// Kernel 2: main fused VQ
// grid: 1024 blocks (256 per group), 256 threads (4 waves), 128 tokens/block
__global__ __launch_bounds__(256, 4)
void vq_main_kernel(const float* __restrict__ lat,
                    const float* __restrict__ w0, const float* __restrict__ w1,
                    const float* __restrict__ w2, const float* __restrict__ w3,
                    float* __restrict__ out, float* __restrict__ ws) {
    __shared__ __align__(16) short lw[2][8192];   // 2 x 16 KB swizzled bf16 chunk
    __shared__ float lwsq[512];
    __shared__ int   sidx[128];

    const int bid   = blockIdx.x;            // 0..1023
    const int g     = bid >> 8;              // 0..3
    const int tbase = (bid & 255) * 128;     // token base within group token space
    const float* wg = (g == 0) ? w0 : (g == 1) ? w1 : (g == 2) ? w2 : w3;
    const char* cbg = (const char*)ws + 65536 + (size_t)g * 65536;
    const float* wsq = ws + 64 + g * 512;

    const int t    = threadIdx.x;
    const int wave = t >> 6;
    const int l    = t & 63;
    const int lr   = l & 15;                 // tile row (A) / col (B,C)
    const int lh   = l >> 4;                 // 0..3: k-partition / C row-block

    lwsq[t]       = wsq[t];
    lwsq[t + 256] = wsq[t + 256];

    // A fragments: 32 tokens per wave (2 m-tiles), bf16; fp32 x_sq on the fly.
    short8 afrag[2][4];
    float  xsq[2];
    const int wtok = tbase + wave * 32;
    #pragma unroll
    for (int mt = 0; mt < 2; mt++) {
        int token = wtok + mt * 16 + lr;
        const float* xp = lat + (size_t)token * 512 + g * 128 + lh * 8;
        float part = 0.f;
        #pragma unroll
        for (int ks = 0; ks < 4; ks++) {
            float4 v0 = *(const float4*)(xp + ks * 32);
            float4 v1 = *(const float4*)(xp + ks * 32 + 4);
            part += v0.x*v0.x + v0.y*v0.y + v0.z*v0.z + v0.w*v0.w
                  + v1.x*v1.x + v1.y*v1.y + v1.z*v1.z + v1.w*v1.w;
            short8 a;
            a[0] = f2bf(v0.x); a[1] = f2bf(v0.y); a[2] = f2bf(v0.z); a[3] = f2bf(v0.w);
            a[4] = f2bf(v1.x); a[5] = f2bf(v1.y); a[6] = f2bf(v1.z); a[7] = f2bf(v1.w);
            afrag[mt][ks] = a;
        }
        part += __shfl_xor(part, 16);
        part += __shfl_xor(part, 32);
        xsq[mt] = part;   // full 128-elem sum; valid per lane row = lr
    }

    // stage codebook chunk (16 KB) into LDS buffer buf: 4 x 1KB issues per wave
    auto stage = [&](int buf, int chunk) {
        const char* gsrc = cbg + chunk * 16384 + wave * 4096 + l * 16;
        char* ldst = (char*)&lw[buf][0] + wave * 4096;
        #pragma unroll
        for (int j = 0; j < 4; j++)
            gload_lds16(gsrc + j * 1024, ldst + j * 1024);
    };

    float runval[8];
    int   runidx[8];
    #pragma unroll
    for (int i = 0; i < 8; i++) { runval[i] = 3.4e38f; runidx[i] = 0; }

    stage(0, 0);
    __syncthreads();   // drains vmcnt(0): chunk 0 resident

    for (int chunk = 0; chunk < 8; chunk++) {
        int buf = chunk & 1;
        if (chunk < 7) stage(buf ^ 1, chunk + 1);   // prefetch next chunk
        const char* lwb = (const char*)&lw[buf][0];
        #pragma unroll
        for (int nt = 0; nt < 4; nt++) {
            short8 bfrag[4];
            int row = nt * 16 + lr;
            int swz = (row & 7) << 4;
            #pragma unroll
            for (int ks = 0; ks < 4; ks++)
                bfrag[ks] = *(const short8*)(lwb + ((row * 256 + ks * 64 + lh * 16) ^ swz));
            int codebase = chunk * 64 + nt * 16;
            float half_wsq = 0.5f * lwsq[codebase + lr];
            #pragma unroll
            for (int mt = 0; mt < 2; mt++) {
                f32x4 acc = {0.f, 0.f, 0.f, 0.f};
                #pragma unroll
                for (int ks = 0; ks < 4; ks++)
                    acc = __builtin_amdgcn_mfma_f32_16x16x32_bf16(afrag[mt][ks], bfrag[ks], acc, 0, 0, 0);
                int code = codebase + lr;
                #pragma unroll
                for (int r = 0; r < 4; r++) {
                    float s = half_wsq - acc[r];   // 0.5*||w||^2 - x.w
                    int i = mt * 4 + r;
                    if (s < runval[i]) { runval[i] = s; runidx[i] = code; }
                }
            }
        }
        __syncthreads();   // all waves done reading buf; next-chunk loads drained
    }

    // argmin across the 16 code-lanes (lr), lexicographic tie-break
    #pragma unroll
    for (int i = 0; i < 8; i++) {
        float v = runval[i]; int id = runidx[i];
        #pragma unroll
        for (int m = 1; m < 16; m <<= 1) {
            float ov = __shfl_xor(v, m);
            int   oi = __shfl_xor(id, m);
            if (ov < v || (ov == v && oi < id)) { v = ov; id = oi; }
        }
        runval[i] = v; runidx[i] = id;
    }

    // per-token min distance, loss accumulation, stash indices
    float lsum = 0.f;
    #pragma unroll
    for (int mt = 0; mt < 2; mt++) {
        #pragma unroll
        for (int r = 0; r < 4; r++) {
            int row = lh * 4 + r;   // row within m-tile owned by this lane-group
            float xs = __shfl(xsq[mt], (l & 48) | row);
            float dist = xs + 2.f * runval[mt * 4 + r];
            if (lr == 0) {
                lsum += dist;
                sidx[wave * 32 + mt * 16 + row] = runidx[mt * 4 + r];
            }
        }
    }
    lsum += __shfl_xor(lsum, 16);
    lsum += __shfl_xor(lsum, 32);
    if (l == 0) atomicAdd(&ws[0], lsum);

    // write q = w[idx] (exact fp32 rows); 1 float4/lane, 512B contiguous per token-quarter
    __syncthreads();
    #pragma unroll
    for (int it = 0; it < 16; it++) {
        int tloc = it * 8 + (t >> 5);
        int idx  = sidx[tloc];
        int col  = (t & 31) * 4;
        float4 v = *(const float4*)(wg + (size_t)idx * 128 + col);
        *(float4*)(out + (size_t)(tbase + tloc) * 512 + g * 128 + col) = v;
    }
}

// Kernel 3: finalize loss
__global__ void vq_finalize_kernel(const float* __restrict__ ws, float* __restrict__ out) {
    out[16777216] = 1.25f * ws[0] * (1.0f / 4194304.0f);
}

extern "C" void kernel_launch(void* const* d_in, const int* in_sizes, int n_in,
                              void* d_out, int out_size, void* d_ws, size_t ws_size,
                              hipStream_t stream) {
    const float* lat = (const float*)d_in[0];
    const float* w1  = (const float*)d_in[1];
    const float* w2  = (const float*)d_in[2];
    const float* w3  = (const float*)d_in[3];
    const float* w4  = (const float*)d_in[4];
    float* out = (float*)d_out;
    float* ws  = (float*)d_ws;

    vq_prep_kernel<<<8, 256, 0, stream>>>(w1, w2, w3, w4, ws);
    vq_main_kernel<<<1024, 256, 0, stream>>>(lat, w1, w2, w3, w4, out, ws);
    vq_finalize_kernel<<<1, 1, 0, stream>>>(ws, out);
}

// Round 3
// 88.033 us; speedup vs baseline: 1.5140x; 1.0931x over previous
//
#include <hip/hip_runtime.h>
#include <stdint.h>

typedef __attribute__((ext_vector_type(8))) short short8;
typedef __attribute__((ext_vector_type(4))) float f32x4;

// fp32 -> bf16 bits, round-to-nearest-even
static __device__ __forceinline__ short f2bf(float f) {
    union { float f; uint32_t u; } v; v.f = f;
    uint32_t u = v.u;
    return (short)((u + 0x7FFFu + ((u >> 16) & 1u)) >> 16);
}

static __device__ __forceinline__ void gload_lds16(const void* g, void* l) {
    __builtin_amdgcn_global_load_lds(
        (const __attribute__((address_space(1))) unsigned int*)g,
        (__attribute__((address_space(3))) unsigned int*)l, 16, 0, 0);
}

// ws layout:
//   ws[0]              : loss accumulator (float)
//   ws[64 .. 64+2048)  : 0.5*||w||^2 per code, group-major (4 x 512)
//   byte 65536 + g*131072 : bf16 codebook for group g, FRAGMENT-MAJOR:
//       16B unit (nt 0..31, ks 0..3, lane 0..63) at ((nt*4+ks)*64 + lane)*16
//       lane = lh*16+lr holds code row nt*16+lr, dims [ks*32+lh*8, +8)
//   -> both global_load_lds staging and ds_read_b128 are perfectly linear.

// Kernel 1: norms + fragment-major bf16 codebook. 2048 threads, one per code.
__global__ void vq_prep_kernel(const float* __restrict__ w0, const float* __restrict__ w1,
                               const float* __restrict__ w2, const float* __restrict__ w3,
                               float* __restrict__ ws) {
    int tid = blockIdx.x * blockDim.x + threadIdx.x; // 0..2047
    if (tid == 0) ws[0] = 0.f;
    const float* wg = (tid < 512) ? w0 : (tid < 1024) ? w1 : (tid < 1536) ? w2 : w3;
    int c  = tid & 511;
    int g  = tid >> 9;
    int nt = c >> 4, lr = c & 15;
    const float* src = wg + (size_t)c * 128;
    char* cb = (char*)ws + 65536 + (size_t)g * 131072;
    float s = 0.f;
    #pragma unroll
    for (int cg = 0; cg < 16; cg++) {        // dim chunk d0 = cg*8
        int ks = cg >> 2, lh = cg & 3;
        float4 v0 = *(const float4*)(src + cg * 8);
        float4 v1 = *(const float4*)(src + cg * 8 + 4);
        s += v0.x*v0.x + v0.y*v0.y + v0.z*v0.z + v0.w*v0.w
           + v1.x*v1.x + v1.y*v1.y + v1.z*v1.z + v1.w*v1.w;
        short8 b;
        b[0] = f2bf(v0.x); b[1] = f2bf(v0.y); b[2] = f2bf(v0.z); b[3] = f2bf(v0.w);
        b[4] = f2bf(v1.x); b[5] = f2bf(v1.y); b[6] = f2bf(v1.z); b[7] = f2bf(v1.w);
        *(short8*)(cb + ((size_t)((nt * 4 + ks) * 64 + lh * 16 + lr) * 16)) = b;
    }
    ws[64 + tid] = 0.5f * s;
}

// Kernel 2: main fused VQ. 256 blocks (64/group) x 1024 threads (16 waves),
// 512 tokens/block (32/wave). Full group codebook resident in LDS.
__global__ __launch_bounds__(1024, 4)
void vq_main_kernel(const float* __restrict__ lat,
                    const float* __restrict__ w0, const float* __restrict__ w1,
                    const float* __restrict__ w2, const float* __restrict__ w3,
                    float* __restrict__ out, float* __restrict__ ws) {
    __shared__ __align__(16) short lw[65536];   // 128 KB codebook, fragment-major
    __shared__ float lwsq[512];

    const int bid   = blockIdx.x;            // 0..255
    const int g     = bid >> 6;              // 0..3
    const int tbase = (bid & 63) * 512;      // token base within group token space
    const float* wg = (g == 0) ? w0 : (g == 1) ? w1 : (g == 2) ? w2 : w3;
    const char* cbg = (const char*)ws + 65536 + (size_t)g * 131072;

    const int t    = threadIdx.x;
    const int wave = t >> 6;                 // 0..15
    const int l    = t & 63;
    const int lr   = l & 15;
    const int lh   = l >> 4;

    if (t < 512) lwsq[t] = ws[64 + g * 512 + t];

    // stage full codebook: wave w owns bytes [w*8192, (w+1)*8192)
    {
        const char* gsrc = cbg + wave * 8192 + l * 16;
        char* ldst = (char*)lw + wave * 8192;
        #pragma unroll
        for (int j = 0; j < 8; j++)
            gload_lds16(gsrc + j * 1024, ldst + j * 1024);
    }

    // A fragments while loads fly: 32 tokens/wave, bf16 + fp32 xsq
    short8 afrag[2][4];
    float  xsq[2];
    const int wtok = tbase + wave * 32;
    #pragma unroll
    for (int mt = 0; mt < 2; mt++) {
        int token = wtok + mt * 16 + lr;
        const float* xp = lat + (size_t)token * 512 + g * 128 + lh * 8;
        float part = 0.f;
        #pragma unroll
        for (int ks = 0; ks < 4; ks++) {
            float4 v0 = *(const float4*)(xp + ks * 32);
            float4 v1 = *(const float4*)(xp + ks * 32 + 4);
            part += v0.x*v0.x + v0.y*v0.y + v0.z*v0.z + v0.w*v0.w
                  + v1.x*v1.x + v1.y*v1.y + v1.z*v1.z + v1.w*v1.w;
            short8 a;
            a[0] = f2bf(v0.x); a[1] = f2bf(v0.y); a[2] = f2bf(v0.z); a[3] = f2bf(v0.w);
            a[4] = f2bf(v1.x); a[5] = f2bf(v1.y); a[6] = f2bf(v1.z); a[7] = f2bf(v1.w);
            afrag[mt][ks] = a;
        }
        part += __shfl_xor(part, 16);
        part += __shfl_xor(part, 32);
        xsq[mt] = part;   // full 128-dim sum; valid per lane token-row = lr
    }

    float runval[8];
    int   runidx[8];
    #pragma unroll
    for (int i = 0; i < 8; i++) { runval[i] = 3.4e38f; runidx[i] = 0; }

    __syncthreads();   // codebook + lwsq resident; only barrier in the kernel

    // barrier-free main loop over 32 n-tiles (512 codes)
    const char* lwb = (const char*)lw + l * 16;
    #pragma unroll 2
    for (int nt = 0; nt < 32; nt++) {
        const char* base = lwb + nt * 4096;
        short8 b0 = *(const short8*)(base);
        short8 b1 = *(const short8*)(base + 1024);
        short8 b2 = *(const short8*)(base + 2048);
        short8 b3 = *(const short8*)(base + 3072);
        float hwsq = lwsq[nt * 16 + lr];     // 0.5*||w||^2
        int   code = nt * 16 + lr;
        #pragma unroll
        for (int mt = 0; mt < 2; mt++) {
            f32x4 acc = {0.f, 0.f, 0.f, 0.f};
            acc = __builtin_amdgcn_mfma_f32_16x16x32_bf16(afrag[mt][0], b0, acc, 0, 0, 0);
            acc = __builtin_amdgcn_mfma_f32_16x16x32_bf16(afrag[mt][1], b1, acc, 0, 0, 0);
            acc = __builtin_amdgcn_mfma_f32_16x16x32_bf16(afrag[mt][2], b2, acc, 0, 0, 0);
            acc = __builtin_amdgcn_mfma_f32_16x16x32_bf16(afrag[mt][3], b3, acc, 0, 0, 0);
            #pragma unroll
            for (int r = 0; r < 4; r++) {
                float s = hwsq - acc[r];     // 0.5*||w||^2 - x.w
                int i = mt * 4 + r;
                if (s < runval[i]) { runval[i] = s; runidx[i] = code; }
            }
        }
    }

    // argmin across the 16 code-lanes (lr bits), lexicographic tie-break
    #pragma unroll
    for (int i = 0; i < 8; i++) {
        float v = runval[i]; int id = runidx[i];
        #pragma unroll
        for (int m = 1; m < 16; m <<= 1) {
            float ov = __shfl_xor(v, m);
            int   oi = __shfl_xor(id, m);
            if (ov < v || (ov == v && oi < id)) { v = ov; id = oi; }
        }
        runval[i] = v; runidx[i] = id;
    }

    // loss: per-token min distance, one atomic per wave
    float lsum = 0.f;
    #pragma unroll
    for (int mt = 0; mt < 2; mt++) {
        #pragma unroll
        for (int r = 0; r < 4; r++) {
            int row = lh * 4 + r;
            float xs = __shfl(xsq[mt], (l & 48) | row);
            if (lr == 0) lsum += xs + 2.f * runval[mt * 4 + r];
        }
    }
    lsum += __shfl_xor(lsum, 16);
    lsum += __shfl_xor(lsum, 32);
    if (l == 0) atomicAdd(&ws[0], lsum);

    // q-write: 2 tokens per iteration, 512B contiguous per token, idx via shfl
    #pragma unroll
    for (int it = 0; it < 16; it++) {
        const int j0 = it * 2, j1 = it * 2 + 1;
        int idx0 = __shfl(runidx[((j0 >> 4) << 2) | (j0 & 3)], ((j0 >> 2) & 3) << 4);
        int idx1 = __shfl(runidx[((j1 >> 4) << 2) | (j1 & 3)], ((j1 >> 2) & 3) << 4);
        int idx  = (l >= 32) ? idx1 : idx0;
        int tloc = it * 2 + (l >> 5);
        int col  = (l & 31) * 4;
        float4 v = *(const float4*)(wg + (size_t)idx * 128 + col);
        *(float4*)(out + (size_t)(wtok + tloc) * 512 + g * 128 + col) = v;
    }
}

// Kernel 3: finalize loss
__global__ void vq_finalize_kernel(const float* __restrict__ ws, float* __restrict__ out) {
    out[16777216] = 1.25f * ws[0] * (1.0f / 4194304.0f);
}

extern "C" void kernel_launch(void* const* d_in, const int* in_sizes, int n_in,
                              void* d_out, int out_size, void* d_ws, size_t ws_size,
                              hipStream_t stream) {
    const float* lat = (const float*)d_in[0];
    const float* w1  = (const float*)d_in[1];
    const float* w2  = (const float*)d_in[2];
    const float* w3  = (const float*)d_in[3];
    const float* w4  = (const float*)d_in[4];
    float* out = (float*)d_out;
    float* ws  = (float*)d_ws;

    vq_prep_kernel<<<8, 256, 0, stream>>>(w1, w2, w3, w4, ws);
    vq_main_kernel<<<256, 1024, 0, stream>>>(lat, w1, w2, w3, w4, out, ws);
    vq_finalize_kernel<<<1, 1, 0, stream>>>(ws, out);
}

// Round 4
// 52.414 us; speedup vs baseline: 2.5428x; 1.6796x over previous
//
#include <hip/hip_runtime.h>
#include <stdint.h>

typedef __attribute__((ext_vector_type(8))) short short8;
typedef __attribute__((ext_vector_type(4))) float f32x4;

// fp32 -> bf16 bits, round-to-nearest-even
static __device__ __forceinline__ short f2bf(float f) {
    union { float f; uint32_t u; } v; v.f = f;
    uint32_t u = v.u;
    return (short)((u + 0x7FFFu + ((u >> 16) & 1u)) >> 16);
}

static __device__ __forceinline__ void gload_lds16(const void* g, void* l) {
    __builtin_amdgcn_global_load_lds(
        (const __attribute__((address_space(1))) unsigned int*)g,
        (__attribute__((address_space(3))) unsigned int*)l, 16, 0, 0);
}

// ws layout:
//   ws[64 .. 64+2048)   : -(0.5*||w||^2) per code, group-major (4 x 512)
//   ws[4096 .. 4096+256): per-block loss partials
//   byte 65536 + g*131072 : bf16 codebook for group g, FRAGMENT-MAJOR:
//       16B unit (nt 0..31, ks 0..3, lane 0..63) at ((nt*4+ks)*64 + lane)*16
//       lane = lh*16+lr holds code row nt*16+lr, dims [ks*32+lh*8, +8)

// Kernel 1: negated half-norms + fragment-major bf16 codebook.
__global__ void vq_prep_kernel(const float* __restrict__ w0, const float* __restrict__ w1,
                               const float* __restrict__ w2, const float* __restrict__ w3,
                               float* __restrict__ ws) {
    int tid = blockIdx.x * blockDim.x + threadIdx.x; // 0..2047
    const float* wg = (tid < 512) ? w0 : (tid < 1024) ? w1 : (tid < 1536) ? w2 : w3;
    int c  = tid & 511;
    int g  = tid >> 9;
    int nt = c >> 4, lr = c & 15;
    const float* src = wg + (size_t)c * 128;
    char* cb = (char*)ws + 65536 + (size_t)g * 131072;
    float s = 0.f;
    #pragma unroll
    for (int cg = 0; cg < 16; cg++) {        // dim chunk d0 = cg*8
        int ks = cg >> 2, lh = cg & 3;
        float4 v0 = *(const float4*)(src + cg * 8);
        float4 v1 = *(const float4*)(src + cg * 8 + 4);
        s += v0.x*v0.x + v0.y*v0.y + v0.z*v0.z + v0.w*v0.w
           + v1.x*v1.x + v1.y*v1.y + v1.z*v1.z + v1.w*v1.w;
        short8 b;
        b[0] = f2bf(v0.x); b[1] = f2bf(v0.y); b[2] = f2bf(v0.z); b[3] = f2bf(v0.w);
        b[4] = f2bf(v1.x); b[5] = f2bf(v1.y); b[6] = f2bf(v1.z); b[7] = f2bf(v1.w);
        *(short8*)(cb + ((size_t)((nt * 4 + ks) * 64 + lh * 16 + lr) * 16)) = b;
    }
    ws[64 + tid] = -0.5f * s;
}

// Kernel 2: main fused VQ. 256 blocks (64/group) x 1024 threads (16 waves),
// 512 tokens/block (32/wave). Full group codebook resident in LDS.
__global__ __launch_bounds__(1024, 4)
void vq_main_kernel(const float* __restrict__ lat,
                    const float* __restrict__ w0, const float* __restrict__ w1,
                    const float* __restrict__ w2, const float* __restrict__ w3,
                    float* __restrict__ out, float* __restrict__ ws) {
    __shared__ __align__(16) short lw[65536];   // 128 KB codebook, fragment-major
    __shared__ float lwsq[512];                  // -(0.5*||w||^2)
    __shared__ float slsum[16];

    const int bid   = blockIdx.x;            // 0..255
    const int g     = bid >> 6;              // 0..3
    const int tbase = (bid & 63) * 512;      // token base within group token space
    const float* wg = (g == 0) ? w0 : (g == 1) ? w1 : (g == 2) ? w2 : w3;
    const char* cbg = (const char*)ws + 65536 + (size_t)g * 131072;

    const int t    = threadIdx.x;
    const int wave = t >> 6;                 // 0..15
    const int l    = t & 63;
    const int lr   = l & 15;
    const int lh   = l >> 4;

    if (t < 512) lwsq[t] = ws[64 + g * 512 + t];

    // stage full codebook: wave w owns bytes [w*8192, (w+1)*8192)
    {
        const char* gsrc = cbg + wave * 8192 + l * 16;
        char* ldst = (char*)lw + wave * 8192;
        #pragma unroll
        for (int j = 0; j < 8; j++)
            gload_lds16(gsrc + j * 1024, ldst + j * 1024);
    }

    // A fragments while loads fly: 32 tokens/wave, bf16 + fp32 xsq
    short8 afrag[2][4];
    float  xsq[2];
    const int wtok = tbase + wave * 32;
    #pragma unroll
    for (int mt = 0; mt < 2; mt++) {
        int token = wtok + mt * 16 + lr;
        const float* xp = lat + (size_t)token * 512 + g * 128 + lh * 8;
        float part = 0.f;
        #pragma unroll
        for (int ks = 0; ks < 4; ks++) {
            float4 v0 = *(const float4*)(xp + ks * 32);
            float4 v1 = *(const float4*)(xp + ks * 32 + 4);
            part += v0.x*v0.x + v0.y*v0.y + v0.z*v0.z + v0.w*v0.w
                  + v1.x*v1.x + v1.y*v1.y + v1.z*v1.z + v1.w*v1.w;
            short8 a;
            a[0] = f2bf(v0.x); a[1] = f2bf(v0.y); a[2] = f2bf(v0.z); a[3] = f2bf(v0.w);
            a[4] = f2bf(v1.x); a[5] = f2bf(v1.y); a[6] = f2bf(v1.z); a[7] = f2bf(v1.w);
            afrag[mt][ks] = a;
        }
        part += __shfl_xor(part, 16);
        part += __shfl_xor(part, 32);
        xsq[mt] = part;   // full 128-dim sum; valid per lane token-row = lr
    }

    float runmax[8];
    int   runidx[8];
    #pragma unroll
    for (int i = 0; i < 8; i++) { runmax[i] = -3.4e38f; runidx[i] = 0; }

    __syncthreads();   // codebook + lwsq resident

    // barrier-free main loop over 32 n-tiles; 2-deep register B-prefetch
    const char* lwb = (const char*)lw + l * 16;
    short8 b0 = *(const short8*)(lwb);
    short8 b1 = *(const short8*)(lwb + 1024);
    short8 b2 = *(const short8*)(lwb + 2048);
    short8 b3 = *(const short8*)(lwb + 3072);
    #pragma unroll 2
    for (int nt = 0; nt < 32; nt++) {
        short8 c0 = b0, c1 = b1, c2 = b2, c3 = b3;
        const char* nbase = lwb + ((nt + 1) & 31) * 4096;
        b0 = *(const short8*)(nbase);
        b1 = *(const short8*)(nbase + 1024);
        b2 = *(const short8*)(nbase + 2048);
        b3 = *(const short8*)(nbase + 3072);
        float h = lwsq[nt * 16 + lr];        // -(0.5*||w||^2) for code nt*16+lr
        int   code = nt * 16 + lr;
        #pragma unroll
        for (int mt = 0; mt < 2; mt++) {
            f32x4 acc = {h, h, h, h};        // acc ends as dot - 0.5*||w||^2
            acc = __builtin_amdgcn_mfma_f32_16x16x32_bf16(afrag[mt][0], c0, acc, 0, 0, 0);
            acc = __builtin_amdgcn_mfma_f32_16x16x32_bf16(afrag[mt][1], c1, acc, 0, 0, 0);
            acc = __builtin_amdgcn_mfma_f32_16x16x32_bf16(afrag[mt][2], c2, acc, 0, 0, 0);
            acc = __builtin_amdgcn_mfma_f32_16x16x32_bf16(afrag[mt][3], c3, acc, 0, 0, 0);
            #pragma unroll
            for (int r = 0; r < 4; r++) {
                int i = mt * 4 + r;
                float s = acc[r];
                if (s > runmax[i]) { runmax[i] = s; runidx[i] = code; }
            }
        }
    }

    // argmax across the 16 code-lanes (lr bits), tie-break lower idx
    #pragma unroll
    for (int i = 0; i < 8; i++) {
        float v = runmax[i]; int id = runidx[i];
        #pragma unroll
        for (int m = 1; m < 16; m <<= 1) {
            float ov = __shfl_xor(v, m);
            int   oi = __shfl_xor(id, m);
            if (ov > v || (ov == v && oi < id)) { v = ov; id = oi; }
        }
        runmax[i] = v; runidx[i] = id;
    }

    // loss: dist = xsq - 2*max(dot - 0.5||w||^2); block-reduce, ONE store/block
    float lsum = 0.f;
    #pragma unroll
    for (int mt = 0; mt < 2; mt++) {
        #pragma unroll
        for (int r = 0; r < 4; r++) {
            int row = lh * 4 + r;
            float xs = __shfl(xsq[mt], (l & 48) | row);
            if (lr == 0) lsum += xs - 2.f * runmax[mt * 4 + r];
        }
    }
    lsum += __shfl_xor(lsum, 16);
    lsum += __shfl_xor(lsum, 32);
    if (l == 0) slsum[wave] = lsum;
    __syncthreads();
    if (t == 0) {
        float s = 0.f;
        #pragma unroll
        for (int i = 0; i < 16; i++) s += slsum[i];
        ws[4096 + bid] = s;
    }

    // q-write: 2 tokens per iteration, 512B contiguous per token, idx via shfl
    #pragma unroll
    for (int it = 0; it < 16; it++) {
        const int j0 = it * 2, j1 = it * 2 + 1;
        int idx0 = __shfl(runidx[((j0 >> 4) << 2) | (j0 & 3)], ((j0 >> 2) & 3) << 4);
        int idx1 = __shfl(runidx[((j1 >> 4) << 2) | (j1 & 3)], ((j1 >> 2) & 3) << 4);
        int idx  = (l >= 32) ? idx1 : idx0;
        int tloc = it * 2 + (l >> 5);
        int col  = (l & 31) * 4;
        float4 v = *(const float4*)(wg + (size_t)idx * 128 + col);
        *(float4*)(out + (size_t)(wtok + tloc) * 512 + g * 128 + col) = v;
    }
}

// Kernel 3: finalize loss — reduce 256 per-block partials
__global__ void vq_finalize_kernel(const float* __restrict__ ws, float* __restrict__ out) {
    __shared__ float s4[4];
    float v = ws[4096 + threadIdx.x];
    #pragma unroll
    for (int m = 1; m < 64; m <<= 1) v += __shfl_xor(v, m);
    if ((threadIdx.x & 63) == 0) s4[threadIdx.x >> 6] = v;
    __syncthreads();
    if (threadIdx.x == 0)
        out[16777216] = 1.25f * (s4[0] + s4[1] + s4[2] + s4[3]) * (1.0f / 4194304.0f);
}

extern "C" void kernel_launch(void* const* d_in, const int* in_sizes, int n_in,
                              void* d_out, int out_size, void* d_ws, size_t ws_size,
                              hipStream_t stream) {
    const float* lat = (const float*)d_in[0];
    const float* w1  = (const float*)d_in[1];
    const float* w2  = (const float*)d_in[2];
    const float* w3  = (const float*)d_in[3];
    const float* w4  = (const float*)d_in[4];
    float* out = (float*)d_out;
    float* ws  = (float*)d_ws;

    vq_prep_kernel<<<8, 256, 0, stream>>>(w1, w2, w3, w4, ws);
    vq_main_kernel<<<256, 1024, 0, stream>>>(lat, w1, w2, w3, w4, out, ws);
    vq_finalize_kernel<<<1, 256, 0, stream>>>(ws, out);
}

// Round 5
// 47.477 us; speedup vs baseline: 2.8073x; 1.1040x over previous
//
#include <hip/hip_runtime.h>
#include <stdint.h>

typedef __attribute__((ext_vector_type(8))) short short8;
typedef __attribute__((ext_vector_type(4))) float f32x4;

// fp32 -> bf16 bits, round-to-nearest-even
static __device__ __forceinline__ short f2bf(float f) {
    union { float f; uint32_t u; } v; v.f = f;
    uint32_t u = v.u;
    return (short)((u + 0x7FFFu + ((u >> 16) & 1u)) >> 16);
}

static __device__ __forceinline__ void gload_lds16(const void* g, void* l) {
    __builtin_amdgcn_global_load_lds(
        (const __attribute__((address_space(1))) unsigned int*)g,
        (__attribute__((address_space(3))) unsigned int*)l, 16, 0, 0);
}

// ws layout:
//   ws[64 .. 64+2048)   : -(0.5*||w||^2) per code, group-major (4 x 512)
//   ws[4096 .. 4096+512): per-block loss partials
//   byte 65536 + g*131072 : bf16 codebook for group g, FRAGMENT-MAJOR:
//       16B unit (nt 0..31, ks 0..3, lane 0..63) at ((nt*4+ks)*64 + lane)*16
//       lane = lh*16+lr holds code row nt*16+lr, dims [ks*32+lh*8, +8)

// Kernel 1: negated half-norms + fragment-major bf16 codebook.
__global__ void vq_prep_kernel(const float* __restrict__ w0, const float* __restrict__ w1,
                               const float* __restrict__ w2, const float* __restrict__ w3,
                               float* __restrict__ ws) {
    int tid = blockIdx.x * blockDim.x + threadIdx.x; // 0..2047
    const float* wg = (tid < 512) ? w0 : (tid < 1024) ? w1 : (tid < 1536) ? w2 : w3;
    int c  = tid & 511;
    int g  = tid >> 9;
    int nt = c >> 4, lr = c & 15;
    const float* src = wg + (size_t)c * 128;
    char* cb = (char*)ws + 65536 + (size_t)g * 131072;
    float s = 0.f;
    #pragma unroll
    for (int cg = 0; cg < 16; cg++) {        // dim chunk d0 = cg*8
        int ks = cg >> 2, lh = cg & 3;
        float4 v0 = *(const float4*)(src + cg * 8);
        float4 v1 = *(const float4*)(src + cg * 8 + 4);
        s += v0.x*v0.x + v0.y*v0.y + v0.z*v0.z + v0.w*v0.w
           + v1.x*v1.x + v1.y*v1.y + v1.z*v1.z + v1.w*v1.w;
        short8 b;
        b[0] = f2bf(v0.x); b[1] = f2bf(v0.y); b[2] = f2bf(v0.z); b[3] = f2bf(v0.w);
        b[4] = f2bf(v1.x); b[5] = f2bf(v1.y); b[6] = f2bf(v1.z); b[7] = f2bf(v1.w);
        *(short8*)(cb + ((size_t)((nt * 4 + ks) * 64 + lh * 16 + lr) * 16)) = b;
    }
    ws[64 + tid] = -0.5f * s;
}

// Kernel 2: main fused VQ. 512 blocks (128/group) x 512 threads (8 waves),
// 256 tokens/block (32/wave). Codebook in LDS as two 64 KB halves (restaged),
// so 2 blocks/CU co-reside and their phases overlap.
__global__ __launch_bounds__(512, 4)
void vq_main_kernel(const float* __restrict__ lat,
                    const float* __restrict__ w0, const float* __restrict__ w1,
                    const float* __restrict__ w2, const float* __restrict__ w3,
                    float* __restrict__ out, float* __restrict__ ws) {
    __shared__ __align__(16) short lw[32768];   // 64 KB: half codebook, fragment-major
    __shared__ float lwsq[512];                  // -(0.5*||w||^2), all 512 codes
    __shared__ float slsum[8];

    const int bid   = blockIdx.x;            // 0..511
    const int g     = bid >> 7;              // 0..3
    const int tbase = (bid & 127) * 256;     // token base within group token space
    const float* wg = (g == 0) ? w0 : (g == 1) ? w1 : (g == 2) ? w2 : w3;
    const char* cbg = (const char*)ws + 65536 + (size_t)g * 131072;

    const int t    = threadIdx.x;
    const int wave = t >> 6;                 // 0..7
    const int l    = t & 63;
    const int lr   = l & 15;
    const int lh   = l >> 4;

    lwsq[t] = ws[64 + g * 512 + t];          // 512 threads -> all 512 norms

    // stage half 0 (codes 0..255): wave w owns bytes [w*8192, (w+1)*8192)
    {
        const char* gsrc = cbg + wave * 8192 + l * 16;
        char* ldst = (char*)lw + wave * 8192;
        #pragma unroll
        for (int j = 0; j < 8; j++)
            gload_lds16(gsrc + j * 1024, ldst + j * 1024);
    }

    // A fragments while loads fly: 32 tokens/wave, bf16 + fp32 xsq
    short8 afrag[2][4];
    float  xsq[2];
    const int wtok = tbase + wave * 32;
    #pragma unroll
    for (int mt = 0; mt < 2; mt++) {
        int token = wtok + mt * 16 + lr;
        const float* xp = lat + (size_t)token * 512 + g * 128 + lh * 8;
        float part = 0.f;
        #pragma unroll
        for (int ks = 0; ks < 4; ks++) {
            float4 v0 = *(const float4*)(xp + ks * 32);
            float4 v1 = *(const float4*)(xp + ks * 32 + 4);
            part += v0.x*v0.x + v0.y*v0.y + v0.z*v0.z + v0.w*v0.w
                  + v1.x*v1.x + v1.y*v1.y + v1.z*v1.z + v1.w*v1.w;
            short8 a;
            a[0] = f2bf(v0.x); a[1] = f2bf(v0.y); a[2] = f2bf(v0.z); a[3] = f2bf(v0.w);
            a[4] = f2bf(v1.x); a[5] = f2bf(v1.y); a[6] = f2bf(v1.z); a[7] = f2bf(v1.w);
            afrag[mt][ks] = a;
        }
        part += __shfl_xor(part, 16);
        part += __shfl_xor(part, 32);
        xsq[mt] = part;   // full 128-dim sum; valid per lane token-row = lr
    }

    float runmax[8];
    int   runidx[8];
    #pragma unroll
    for (int i = 0; i < 8; i++) { runmax[i] = -3.4e38f; runidx[i] = 0; }

    const char* lwb = (const char*)lw + l * 16;

    #pragma unroll
    for (int h = 0; h < 2; h++) {
        __syncthreads();   // half-h staging drained (and, for h=1, readers of half-0 done)

        // 2-deep register B-prefetch over this half's 16 n-tiles
        short8 b0 = *(const short8*)(lwb);
        short8 b1 = *(const short8*)(lwb + 1024);
        short8 b2 = *(const short8*)(lwb + 2048);
        short8 b3 = *(const short8*)(lwb + 3072);
        #pragma unroll 2
        for (int nt = 0; nt < 16; nt++) {
            short8 c0 = b0, c1 = b1, c2 = b2, c3 = b3;
            const char* nbase = lwb + ((nt + 1) & 15) * 4096;
            b0 = *(const short8*)(nbase);
            b1 = *(const short8*)(nbase + 1024);
            b2 = *(const short8*)(nbase + 2048);
            b3 = *(const short8*)(nbase + 3072);
            int  gnt  = h * 16 + nt;
            float hn  = lwsq[gnt * 16 + lr];     // -(0.5*||w||^2)
            int  code = gnt * 16 + lr;
            #pragma unroll
            for (int mt = 0; mt < 2; mt++) {
                f32x4 acc = {hn, hn, hn, hn};    // ends as dot - 0.5*||w||^2
                acc = __builtin_amdgcn_mfma_f32_16x16x32_bf16(afrag[mt][0], c0, acc, 0, 0, 0);
                acc = __builtin_amdgcn_mfma_f32_16x16x32_bf16(afrag[mt][1], c1, acc, 0, 0, 0);
                acc = __builtin_amdgcn_mfma_f32_16x16x32_bf16(afrag[mt][2], c2, acc, 0, 0, 0);
                acc = __builtin_amdgcn_mfma_f32_16x16x32_bf16(afrag[mt][3], c3, acc, 0, 0, 0);
                #pragma unroll
                for (int r = 0; r < 4; r++) {
                    int i = mt * 4 + r;
                    float s = acc[r];
                    if (s > runmax[i]) { runmax[i] = s; runidx[i] = code; }
                }
            }
        }

        if (h == 0) {
            __syncthreads();   // all waves done reading half 0
            const char* gsrc = cbg + 65536 + wave * 8192 + l * 16;
            char* ldst = (char*)lw + wave * 8192;
            #pragma unroll
            for (int j = 0; j < 8; j++)
                gload_lds16(gsrc + j * 1024, ldst + j * 1024);
        }
    }

    // argmax across the 16 code-lanes (lr bits), tie-break lower idx
    #pragma unroll
    for (int i = 0; i < 8; i++) {
        float v = runmax[i]; int id = runidx[i];
        #pragma unroll
        for (int m = 1; m < 16; m <<= 1) {
            float ov = __shfl_xor(v, m);
            int   oi = __shfl_xor(id, m);
            if (ov > v || (ov == v && oi < id)) { v = ov; id = oi; }
        }
        runmax[i] = v; runidx[i] = id;
    }

    // loss: dist = xsq - 2*max(dot - 0.5||w||^2); block-reduce, ONE store/block
    float lsum = 0.f;
    #pragma unroll
    for (int mt = 0; mt < 2; mt++) {
        #pragma unroll
        for (int r = 0; r < 4; r++) {
            int row = lh * 4 + r;
            float xs = __shfl(xsq[mt], (l & 48) | row);
            if (lr == 0) lsum += xs - 2.f * runmax[mt * 4 + r];
        }
    }
    lsum += __shfl_xor(lsum, 16);
    lsum += __shfl_xor(lsum, 32);
    if (l == 0) slsum[wave] = lsum;
    __syncthreads();
    if (t == 0) {
        float s = 0.f;
        #pragma unroll
        for (int i = 0; i < 8; i++) s += slsum[i];
        ws[4096 + bid] = s;
    }

    // q-write: 2 tokens per iteration, 512B contiguous per token, idx via shfl
    #pragma unroll
    for (int it = 0; it < 16; it++) {
        const int j0 = it * 2, j1 = it * 2 + 1;
        int idx0 = __shfl(runidx[((j0 >> 4) << 2) | (j0 & 3)], ((j0 >> 2) & 3) << 4);
        int idx1 = __shfl(runidx[((j1 >> 4) << 2) | (j1 & 3)], ((j1 >> 2) & 3) << 4);
        int idx  = (l >= 32) ? idx1 : idx0;
        int tloc = it * 2 + (l >> 5);
        int col  = (l & 31) * 4;
        float4 v = *(const float4*)(wg + (size_t)idx * 128 + col);
        *(float4*)(out + (size_t)(wtok + tloc) * 512 + g * 128 + col) = v;
    }
}

// Kernel 3: finalize loss — reduce 512 per-block partials
__global__ void vq_finalize_kernel(const float* __restrict__ ws, float* __restrict__ out) {
    __shared__ float s8[8];
    float v = ws[4096 + threadIdx.x];
    #pragma unroll
    for (int m = 1; m < 64; m <<= 1) v += __shfl_xor(v, m);
    if ((threadIdx.x & 63) == 0) s8[threadIdx.x >> 6] = v;
    __syncthreads();
    if (threadIdx.x == 0) {
        float s = 0.f;
        #pragma unroll
        for (int i = 0; i < 8; i++) s += s8[i];
        out[16777216] = 1.25f * s * (1.0f / 4194304.0f);
    }
}

extern "C" void kernel_launch(void* const* d_in, const int* in_sizes, int n_in,
                              void* d_out, int out_size, void* d_ws, size_t ws_size,
                              hipStream_t stream) {
    const float* lat = (const float*)d_in[0];
    const float* w1  = (const float*)d_in[1];
    const float* w2  = (const float*)d_in[2];
    const float* w3  = (const float*)d_in[3];
    const float* w4  = (const float*)d_in[4];
    float* out = (float*)d_out;
    float* ws  = (float*)d_ws;

    vq_prep_kernel<<<8, 256, 0, stream>>>(w1, w2, w3, w4, ws);
    vq_main_kernel<<<512, 512, 0, stream>>>(lat, w1, w2, w3, w4, out, ws);
    vq_finalize_kernel<<<1, 512, 0, stream>>>(ws, out);
}